// Round 6
// baseline (213.156 us; speedup 1.0000x reference)
//
#include <hip/hip_runtime.h>
#include <cmath>

typedef __attribute__((ext_vector_type(8))) short short8;
typedef __attribute__((ext_vector_type(4))) short short4v;
typedef __attribute__((ext_vector_type(16))) float floatx16;
typedef __attribute__((ext_vector_type(4))) float float4v;
typedef unsigned short ushort_t;

#define LSEQ   2048
#define DMODEL 1024
#define BM 128
#define BN 128
#define BK 64
#define TPAD 136   // transpose LDS row stride (elems); 272 B, 16-B aligned

// log2(0.96875)
#define L2GAMMA (-0.045803595f)
// log2(10000)/512
#define L2E4_512 (0.0259525632f)

// float -> bf16 with round-to-nearest-even
__device__ __forceinline__ ushort_t f2b(float x) {
    union { float f; unsigned u; } v; v.f = x;
    unsigned r = v.u + 0x7fffu + ((v.u >> 16) & 1u);
    return (ushort_t)(r >> 16);
}

#define GLOAD_LDS16(gptr, lptr)                                                     \
    __builtin_amdgcn_global_load_lds(                                               \
        (const __attribute__((address_space(1))) unsigned int*)(gptr),              \
        (__attribute__((address_space(3))) unsigned int*)(lptr), 16, 0, 0)

#define MFMA_B16 __builtin_amdgcn_mfma_f32_32x32x16_bf16
#define MFMA16   __builtin_amdgcn_mfma_f32_16x16x32_bf16

// ---------------------------------------------------------------------------
// GEMM core (32x32x16, 128x128 tile, 4 waves): used by score/av kernels.
// C(128x128) += A[aRow0..][k] * B[bRow0..][k]^T, BK=64, single LDS buffer
// pair, (row&7) XOR chunk swizzle.
// ---------------------------------------------------------------------------
__device__ __forceinline__ void gemm_core(
    const ushort_t* __restrict__ Ag, int lda, int aRow0,
    const ushort_t* __restrict__ Bg, int ldb, int bRow0,
    int kDepth, ushort_t* As, ushort_t* Bs, floatx16 acc[2][2])
{
    const int tid  = threadIdx.x;
    const int wave = tid >> 6, lane = tid & 63;
    const int wm = wave >> 1, wn = wave & 1;
    const int l31 = lane & 31, half = lane >> 5;
    const int srow = lane >> 3;                       // 0..7 within 8-row group
    const int scol = ((lane & 7) ^ srow) * 8;         // swizzled source chunk

    const ushort_t* ap[4];
    const ushort_t* bp[4];
    #pragma unroll
    for (int L = 0; L < 4; ++L) {
        int r = (wave * 4 + L) * 8 + srow;            // 0..127
        ap[L] = Ag + (size_t)(aRow0 + r) * lda + scol;
        bp[L] = Bg + (size_t)(bRow0 + r) * ldb + scol;
    }
    const int ldst = (lane >> 3) * BK + (lane & 7) * 8;

    for (int k0 = 0; k0 < kDepth; k0 += BK) {
        __syncthreads();
        #pragma unroll
        for (int L = 0; L < 4; ++L) {
            GLOAD_LDS16(ap[L], As + (wave * 4 + L) * (8 * BK) + ldst);
            GLOAD_LDS16(bp[L], Bs + (wave * 4 + L) * (8 * BK) + ldst);
            ap[L] += BK; bp[L] += BK;
        }
        __syncthreads();

        #pragma unroll
        for (int ks = 0; ks < 4; ++ks) {
            const int ch = ((ks * 2 + half) ^ (l31 & 7)) * 8;  // un-swizzle
            short8 a0 = *(const short8*)(As + (wm * 64      + l31) * BK + ch);
            short8 a1 = *(const short8*)(As + (wm * 64 + 32 + l31) * BK + ch);
            short8 b0 = *(const short8*)(Bs + (wn * 64      + l31) * BK + ch);
            short8 b1 = *(const short8*)(Bs + (wn * 64 + 32 + l31) * BK + ch);
            acc[0][0] = MFMA_B16(a0, b0, acc[0][0], 0, 0, 0);
            acc[0][1] = MFMA_B16(a0, b1, acc[0][1], 0, 0, 0);
            acc[1][0] = MFMA_B16(a1, b0, acc[1][0], 0, 0, 0);
            acc[1][1] = MFMA_B16(a1, b1, acc[1][1], 0, 0, 0);
        }
    }
}
// 32x32x16 C/D layout: col = lane&31 (+ni*32), row = (reg&3) + 8*(reg>>2) +
// 4*(lane>>5) (+mi*32).

// ---------------------------------------------------------------------------
// Prep: xpos (cos,sin) tables with xpos-scale AND decay gamma^{+-l} folded in.
// ---------------------------------------------------------------------------
__global__ __launch_bounds__(256) void xpos_table_kernel(float2* __restrict__ T)
{
    int idx = blockIdx.x * 256 + threadIdx.x;   // 2*512*2048 entries
    int l = idx & 2047;
    int p = (idx >> 11) & 511;
    int mode = idx >> 20;
    float sv = (2.0f * (float)p + 409.6f) * (1.0f / 1433.6f);
    float coeff = log2f(sv) * (1.0f / 512.0f) + L2GAMMA;
    float invf = exp2f(-(float)p * L2E4_512);
    float lf = (float)l;
    float s, c;
    sincosf(lf * invf, &s, &c);
    float g = exp2f((mode == 0 ? lf : -lf) * coeff);
    T[idx] = make_float2(c * g, s * g);
}

// ---------------------------------------------------------------------------
// Prep: fp32 -> bf16 cast of X
// ---------------------------------------------------------------------------
__global__ __launch_bounds__(256) void cast_x_kernel(
    const float4* __restrict__ X, short4v* __restrict__ Xb, int n4)
{
    int i = blockIdx.x * 256 + threadIdx.x;
    if (i < n4) {
        float4 v = X[i];
        short4v o;
        o.x = (short)f2b(v.x); o.y = (short)f2b(v.y);
        o.z = (short)f2b(v.z); o.w = (short)f2b(v.w);
        Xb[i] = o;
    }
}

// ---------------------------------------------------------------------------
// Prep: W (fp32 [K][N]) -> Wt (bf16 [N][K]) for all three weights
// ---------------------------------------------------------------------------
__global__ __launch_bounds__(256) void wtrans_kernel(
    const float* __restrict__ Wq, const float* __restrict__ Wk,
    const float* __restrict__ Wv, ushort_t* __restrict__ Wt)
{
    const float* W = blockIdx.z == 0 ? Wq : blockIdx.z == 1 ? Wk : Wv;
    ushort_t* O = Wt + (size_t)blockIdx.z * (DMODEL * DMODEL);
    __shared__ float t[32][33];
    const int x = threadIdx.x & 31, y = (threadIdx.x >> 5) * 4;
    const int k0 = blockIdx.y * 32, n0 = blockIdx.x * 32;
    #pragma unroll
    for (int j = 0; j < 4; ++j)
        t[y + j][x] = W[(size_t)(k0 + y + j) * DMODEL + n0 + x];
    __syncthreads();
    #pragma unroll
    for (int j = 0; j < 4; ++j)
        O[(size_t)(n0 + y + j) * DMODEL + k0 + x] = f2b(t[x][y + j]);
}

// ---------------------------------------------------------------------------
// Stage 1 (v6): QKV projection, m97-structure core.
// 128x128 tile, 256 threads (4 waves, 2x2 of 64x64), 16x16x32 MFMA with
// 4x4 fragment grid per wave -> 8 ds_read_b128 per K=32 half for 16 MFMA
// (0.5 reads/MFMA, half of the 32x32-path's 1.0). acc = 64 regs/wave.
// Simple 2-barrier K-loop (compiler schedules lgkmcnt; TLP from 2-4
// blocks/CU hides the barrier drain -- no forced launch bounds).
// Operand layout (16x16x32): lane holds M/N index = lane&15, k-group =
// lane>>4 (8 elems each); C/D: col = lane&15 (+fc*16), row = (lane>>4)*4 + q
// (+fr*16)  [m89-verified].
// ---------------------------------------------------------------------------
__global__ __launch_bounds__(256) void qkv16_kernel(
    const ushort_t* __restrict__ Xb, const ushort_t* __restrict__ Wt,
    const float2* __restrict__ Tab,
    ushort_t* __restrict__ Q, ushort_t* __restrict__ Ko, ushort_t* __restrict__ Vt)
{
    __shared__ ushort_t smem[128 * TPAD];   // 34816 B; staging uses first 32 KB
    ushort_t* As = smem;                    // [128][64]
    ushort_t* Bs = smem + BM * BK;          // [128][64]

    // XCD-bijective swizzle (grid % 8 == 0) + 8x8 supertile decode
    const int nwg = gridDim.x;
    const int orig = blockIdx.x;
    const int lin = (orig & 7) * (nwg >> 3) + (orig >> 3);
    const int inner = lin & 63;
    const int sup = lin >> 6;
    const int c = (sup % 3) * 8 + (inner & 7);     // 0..23
    const int r = (sup / 3) * 8 + (inner >> 3);
    const int mode = c >> 3;
    const int c0 = (c & 7) * BN;
    const int row0 = r * BM;

    const int tid = threadIdx.x;
    const int wave = tid >> 6, lane = tid & 63;
    const int wm = wave >> 1, wn = wave & 1;
    const int l15 = lane & 15, l4g = lane >> 4, l7 = lane & 7;

    // staging: 16B chunks, XOR-swizzled by row&7, 32-bit voffsets
    const int srow = lane >> 3;
    const int scol = ((lane & 7) ^ srow) * 8;
    const char* gA = (const char*)Xb;
    const char* gB = (const char*)(Wt + (size_t)mode * (DMODEL * DMODEL));
    unsigned aoff[4], boff[4];
    #pragma unroll
    for (int L = 0; L < 4; ++L) {
        const int rr = (wave * 4 + L) * 8 + srow;       // 0..127
        aoff[L] = (unsigned)(((row0 + rr) * DMODEL + scol) * 2);
        boff[L] = (unsigned)(((c0 + rr) * DMODEL + scol) * 2);
    }
    const int ldst = srow * BK + (lane & 7) * 8;        // == lane*16 bytes

    // compute-read bases: frag f at k-half h:
    //   elem = (q64 + f*16 + l15)*64 + ((h*4 + l4g) ^ l7)*8
    // (row&7 == l7 since q64, f*16 are multiples of 8/16)
    int aBase[2], bBase[2];
    #pragma unroll
    for (int h = 0; h < 2; ++h) {
        const int ch = ((h * 4 + l4g) ^ l7) * 8;
        aBase[h] = (wm * 64 + l15) * BK + ch;
        bBase[h] = (wn * 64 + l15) * BK + ch;
    }

    float4v acc[4][4] = {};

    for (int k0 = 0; k0 < DMODEL; k0 += BK) {
        __syncthreads();
        #pragma unroll
        for (int L = 0; L < 4; ++L) {
            GLOAD_LDS16(gA + aoff[L], As + (wave * 4 + L) * (8 * BK) + ldst);
            GLOAD_LDS16(gB + boff[L], Bs + (wave * 4 + L) * (8 * BK) + ldst);
            aoff[L] += 2 * BK; boff[L] += 2 * BK;
        }
        __syncthreads();

        #pragma unroll
        for (int h = 0; h < 2; ++h) {
            short8 a[4], b[4];
            #pragma unroll
            for (int f = 0; f < 4; ++f) {
                a[f] = *(const short8*)(As + aBase[h] + f * (16 * BK));
                b[f] = *(const short8*)(Bs + bBase[h] + f * (16 * BK));
            }
            #pragma unroll
            for (int fr = 0; fr < 4; ++fr)
                #pragma unroll
                for (int fc = 0; fc < 4; ++fc)
                    acc[fr][fc] = MFMA16(a[fr], b[fc], acc[fr][fc], 0, 0, 0);
        }
    }

    const int rB = row0 + wm * 64 + l4g * 4;   // + fr*16 + q
    const int cB = c0 + wn * 64 + l15;         // + fc*16

    if (mode < 2) {
        ushort_t* O = (mode == 0) ? Q : Ko;
        const float2* Tm = Tab + (size_t)mode * (512 * 2048);
        #pragma unroll
        for (int fc = 0; fc < 4; ++fc) {
            const int col = cB + fc * 16;
            const float2* tp = Tm + ((size_t)(col >> 1) << 11);
            #pragma unroll
            for (int fr = 0; fr < 4; ++fr) {
                const int row = rB + fr * 16;
                const int l0 = row & 2047;                   // multiple of 4
                float4 t01 = *(const float4*)(tp + l0);      // (c0,s0,c1,s1)
                float4 t23 = *(const float4*)(tp + l0 + 2);  // (c2,s2,c3,s3)
                float cs[8] = {t01.x, t01.y, t01.z, t01.w,
                               t23.x, t23.y, t23.z, t23.w};
                #pragma unroll
                for (int q = 0; q < 4; ++q) {
                    float v  = acc[fr][fc][q];
                    float pv = __shfl_xor(v, 1);   // lanes l,l^1 = cols c,c^1
                    float cc = cs[2 * q], ss = cs[2 * q + 1];
                    float res = (lane & 1) ? fmaf(v, cc, pv * ss)
                                           : fmaf(v, cc, -pv * ss);
                    O[(size_t)(row + q) * DMODEL + col] = f2b(res);
                }
            }
        }
    } else {
        // V: transpose tile in LDS (bf16, padded rows), then contiguous stores
        __syncthreads();   // all waves' reads of As/Bs done; safe to reuse smem
        #pragma unroll
        for (int fc = 0; fc < 4; ++fc)
            #pragma unroll
            for (int fr = 0; fr < 4; ++fr) {
                short4v pk;
                pk.x = (short)f2b(acc[fr][fc][0]);
                pk.y = (short)f2b(acc[fr][fc][1]);
                pk.z = (short)f2b(acc[fr][fc][2]);
                pk.w = (short)f2b(acc[fr][fc][3]);
                *(short4v*)(smem + (wn * 64 + fc * 16 + l15) * TPAD
                                 + wm * 64 + fr * 16 + l4g * 4) = pk;
            }
        __syncthreads();
        // thread t: col = t>>1, row-half = (t&1)*64; 128 B contiguous stores
        const int t = threadIdx.x;
        const int colV = c0 + (t >> 1);
        const int lhalf = (t & 1) * 64;
        const int b = row0 >> 11, lpos0 = (row0 & 2047) + lhalf;
        #pragma unroll
        for (int i = 0; i < 8; ++i) {
            short8 vv = *(const short8*)(smem + (t >> 1) * TPAD + lhalf + i * 8);
            *(short8*)(Vt + (size_t)b * (LSEQ * DMODEL)
                          + (size_t)colV * LSEQ + lpos0 + i * 8) = vv;
        }
    }
}

// ---------------------------------------------------------------------------
// Stage 2: S = Q-hat . K-hat^T (decay pre-folded), banded: only tiles with
// bi-2 <= bj <= bi. 45 tiles per batch.
// ---------------------------------------------------------------------------
__global__ __launch_bounds__(256, 4) void score_kernel(
    const ushort_t* __restrict__ Q, const ushort_t* __restrict__ Kc,
    ushort_t* __restrict__ S)
{
    const int t = blockIdx.x, z = blockIdx.z;
    int bi, bj;
    if (t < 3) { bi = (t > 0); bj = t - (t > 0); }
    else { int u = t - 3; bi = 2 + u / 3; bj = bi - 2 + u % 3; }

    __shared__ ushort_t As[BM * BK], Bs[BN * BK];
    floatx16 acc[2][2] = {};
    const size_t zoff = (size_t)z * (LSEQ * DMODEL);
    gemm_core(Q + zoff, DMODEL, bi * BM, Kc + zoff, DMODEL, bj * BN,
              DMODEL, As, Bs, acc);

    const int wave = threadIdx.x >> 6, lane = threadIdx.x & 63;
    const int wm = wave >> 1, wn = wave & 1;
    const int l31 = lane & 31, half = lane >> 5;
    const int nBase = bi * BM + wm * 64 + 4 * half;
    const int mBase = bj * BN + wn * 64 + l31;
    ushort_t* Sz = S + (size_t)z * LSEQ * LSEQ;
    #pragma unroll
    for (int mi = 0; mi < 2; ++mi)
        #pragma unroll
        for (int ni = 0; ni < 2; ++ni) {
            int m = mBase + ni * 32;
            #pragma unroll
            for (int rg = 0; rg < 4; ++rg)
                #pragma unroll
                for (int q = 0; q < 4; ++q) {
                    int n = nBase + mi * 32 + 8 * rg + q;
                    Sz[(size_t)n * LSEQ + m] =
                        (m <= n) ? f2b(acc[mi][ni][rg * 4 + q]) : (ushort_t)0;
                }
        }
}

// ---------------------------------------------------------------------------
// Stage 3: O = S @ V, banded k-window [max(0,(bi-2)*128), (bi+1)*128).
// ---------------------------------------------------------------------------
__global__ __launch_bounds__(256, 4) void av_kernel(
    const ushort_t* __restrict__ S, const ushort_t* __restrict__ Vt,
    float* __restrict__ Out)
{
    const int bx = blockIdx.x, bi = blockIdx.y, z = blockIdx.z;
    const int kLo = (bi >= 2) ? (bi - 2) * BM : 0;
    const int kW  = (bi + 1) * BM - kLo;          // 128, 256, or 384
    __shared__ ushort_t As[BM * BK], Bs[BN * BK];
    floatx16 acc[2][2] = {};
    gemm_core(S + (size_t)z * LSEQ * LSEQ + kLo, LSEQ, bi * BM,
              Vt + (size_t)z * (LSEQ * DMODEL) + kLo, LSEQ, bx * BN,
              kW, As, Bs, acc);

    const int wave = threadIdx.x >> 6, lane = threadIdx.x & 63;
    const int wm = wave >> 1, wn = wave & 1;
    const int l31 = lane & 31, half = lane >> 5;
    const int rBase = bi * BM + wm * 64 + 4 * half;
    const int cBase = bx * BN + wn * 64 + l31;
    float* Oz = Out + (size_t)z * (LSEQ * DMODEL);
    #pragma unroll
    for (int mi = 0; mi < 2; ++mi)
        #pragma unroll
        for (int ni = 0; ni < 2; ++ni)
            #pragma unroll
            for (int rg = 0; rg < 4; ++rg)
                #pragma unroll
                for (int q = 0; q < 4; ++q)
                    Oz[(size_t)(rBase + mi * 32 + 8 * rg + q) * DMODEL
                       + cBase + ni * 32] = acc[mi][ni][rg * 4 + q];
}

// ---------------------------------------------------------------------------
extern "C" void kernel_launch(void* const* d_in, const int* in_sizes, int n_in,
                              void* d_out, int out_size, void* d_ws, size_t ws_size,
                              hipStream_t stream)
{
    const float* X  = (const float*)d_in[0];
    const float* Wq = (const float*)d_in[1];
    const float* Wk = (const float*)d_in[2];
    const float* Wv = (const float*)d_in[3];
    float* out = (float*)d_out;

    const size_t LH  = (size_t)LSEQ * DMODEL;     // 2,097,152 elems / batch
    const size_t WSZ = (size_t)DMODEL * DMODEL;   // 1,048,576 elems / weight
    const size_t SSZ = (size_t)LSEQ * LSEQ;       // 4,194,304 elems / batch
    const size_t TABN = (size_t)2 * 512 * 2048;   // float2 entries

    size_t need4 = TABN * 8 + 2 * (3 * WSZ + 4 * (4 * LH + SSZ));  // ~124 MB
    const int bs = (ws_size >= need4) ? 4 : 1;

    float2* Tab = (float2*)d_ws;
    ushort_t* ws16 = (ushort_t*)(Tab + TABN);
    ushort_t* Wt = ws16;
    ushort_t* Xb = Wt + 3 * WSZ;
    ushort_t* Q  = Xb + (size_t)bs * LH;
    ushort_t* Kb = Q  + (size_t)bs * LH;
    ushort_t* Vt = Kb + (size_t)bs * LH;
    ushort_t* S  = Vt + (size_t)bs * LH;

    xpos_table_kernel<<<dim3(TABN / 256), 256, 0, stream>>>(Tab);
    wtrans_kernel<<<dim3(32, 32, 3), 256, 0, stream>>>(Wq, Wk, Wv, Wt);

    for (int p = 0; p < 4 / bs; ++p) {
        const float* Xp = X + (size_t)p * bs * LH;
        cast_x_kernel<<<dim3(bs * 2048), 256, 0, stream>>>(
            (const float4*)Xp, (short4v*)Xb, bs * (int)(LH / 4));
        qkv16_kernel<<<dim3(24 * bs * 16), 256, 0, stream>>>(
            Xb, Wt, Tab, Q, Kb, Vt);
        score_kernel<<<dim3(45, 1, bs), 256, 0, stream>>>(Q, Kb, S);
        av_kernel<<<dim3(8, 16, bs), 256, 0, stream>>>(S, Vt,
            out + (size_t)p * bs * LH);
    }
}

// Round 7
// 201.816 us; speedup vs baseline: 1.0562x; 1.0562x over previous
//
#include <hip/hip_runtime.h>
#include <cmath>

typedef __attribute__((ext_vector_type(8))) short short8;
typedef __attribute__((ext_vector_type(4))) short short4v;
typedef __attribute__((ext_vector_type(16))) float floatx16;
typedef __attribute__((ext_vector_type(4))) float float4v;
typedef unsigned short ushort_t;

#define LSEQ   2048
#define DMODEL 1024
#define BM 128
#define BN 128
#define BK 64
#define TPAD 136   // transpose LDS row stride (elems); 272 B, 16-B aligned

// log2(0.96875)
#define L2GAMMA (-0.045803595f)
// log2(10000)/512
#define L2E4_512 (0.0259525632f)

// float -> bf16 with round-to-nearest-even
__device__ __forceinline__ ushort_t f2b(float x) {
    union { float f; unsigned u; } v; v.f = x;
    unsigned r = v.u + 0x7fffu + ((v.u >> 16) & 1u);
    return (ushort_t)(r >> 16);
}

#define GLOAD_LDS16(gptr, lptr)                                                     \
    __builtin_amdgcn_global_load_lds(                                               \
        (const __attribute__((address_space(1))) unsigned int*)(gptr),              \
        (__attribute__((address_space(3))) unsigned int*)(lptr), 16, 0, 0)

#define MFMA_B16 __builtin_amdgcn_mfma_f32_32x32x16_bf16
#define MFMA16   __builtin_amdgcn_mfma_f32_16x16x32_bf16

// ---------------------------------------------------------------------------
// GEMM core (32x32x16, 128x128 tile, 4 waves): used by score/av kernels.
// v7: DOUBLE-BUFFERED staging with counted vmcnt + raw barriers (no
// __syncthreads -> no forced vmcnt(0) drain per iter). As/Bs must each be
// sized 2*BM*BK. Ledger per wave per iter: enter with 8 in flight (tile j);
// stage 8 for tile j+1 -> 16; vmcnt(8) retires tile j's; barrier; compute;
// barrier. Buffer j+1's region was last read at iter j-1, whose reads
// completed before that iter's trailing barrier -> overwrite safe.
// ---------------------------------------------------------------------------
__device__ __forceinline__ void gemm_core(
    const ushort_t* __restrict__ Ag, int lda, int aRow0,
    const ushort_t* __restrict__ Bg, int ldb, int bRow0,
    int kDepth, ushort_t* As, ushort_t* Bs, floatx16 acc[2][2])
{
    const int tid  = threadIdx.x;
    const int wave = tid >> 6, lane = tid & 63;
    const int wm = wave >> 1, wn = wave & 1;
    const int l31 = lane & 31, half = lane >> 5;
    const int srow = lane >> 3;                       // 0..7 within 8-row group
    const int scol = ((lane & 7) ^ srow) * 8;         // swizzled source chunk

    const ushort_t* ap[4];
    const ushort_t* bp[4];
    #pragma unroll
    for (int L = 0; L < 4; ++L) {
        int r = (wave * 4 + L) * 8 + srow;            // 0..127
        ap[L] = Ag + (size_t)(aRow0 + r) * lda + scol;
        bp[L] = Bg + (size_t)(bRow0 + r) * ldb + scol;
    }
    const int ldst = srow * BK + (lane & 7) * 8;

    const int nt = kDepth / BK;
    // stage tile 0 -> buf 0
    #pragma unroll
    for (int L = 0; L < 4; ++L) {
        GLOAD_LDS16(ap[L], As + (wave * 4 + L) * (8 * BK) + ldst);
        GLOAD_LDS16(bp[L], Bs + (wave * 4 + L) * (8 * BK) + ldst);
        ap[L] += BK; bp[L] += BK;
    }

    for (int j = 0; j < nt; ++j) {
        const int cur = (j & 1) * (BM * BK);
        const int nxt = ((j + 1) & 1) * (BM * BK);
        if (j + 1 < nt) {
            #pragma unroll
            for (int L = 0; L < 4; ++L) {
                GLOAD_LDS16(ap[L], As + nxt + (wave * 4 + L) * (8 * BK) + ldst);
                GLOAD_LDS16(bp[L], Bs + nxt + (wave * 4 + L) * (8 * BK) + ldst);
                ap[L] += BK; bp[L] += BK;
            }
            asm volatile("s_waitcnt vmcnt(8)" ::: "memory");
        } else {
            asm volatile("s_waitcnt vmcnt(0)" ::: "memory");
        }
        __builtin_amdgcn_s_barrier();
        asm volatile("" ::: "memory");

        #pragma unroll
        for (int ks = 0; ks < 4; ++ks) {
            const int ch = ((ks * 2 + half) ^ (l31 & 7)) * 8;  // un-swizzle
            short8 a0 = *(const short8*)(As + cur + (wm * 64      + l31) * BK + ch);
            short8 a1 = *(const short8*)(As + cur + (wm * 64 + 32 + l31) * BK + ch);
            short8 b0 = *(const short8*)(Bs + cur + (wn * 64      + l31) * BK + ch);
            short8 b1 = *(const short8*)(Bs + cur + (wn * 64 + 32 + l31) * BK + ch);
            acc[0][0] = MFMA_B16(a0, b0, acc[0][0], 0, 0, 0);
            acc[0][1] = MFMA_B16(a0, b1, acc[0][1], 0, 0, 0);
            acc[1][0] = MFMA_B16(a1, b0, acc[1][0], 0, 0, 0);
            acc[1][1] = MFMA_B16(a1, b1, acc[1][1], 0, 0, 0);
        }
        asm volatile("" ::: "memory");
        __builtin_amdgcn_s_barrier();
    }
}
// 32x32x16 C/D layout: col = lane&31 (+ni*32), row = (reg&3) + 8*(reg>>2) +
// 4*(lane>>5) (+mi*32).

// ---------------------------------------------------------------------------
// Prep: xpos (cos,sin) tables with xpos-scale AND decay gamma^{+-l} folded in.
// ---------------------------------------------------------------------------
__global__ __launch_bounds__(256) void xpos_table_kernel(float2* __restrict__ T)
{
    int idx = blockIdx.x * 256 + threadIdx.x;   // 2*512*2048 entries
    int l = idx & 2047;
    int p = (idx >> 11) & 511;
    int mode = idx >> 20;
    float sv = (2.0f * (float)p + 409.6f) * (1.0f / 1433.6f);
    float coeff = log2f(sv) * (1.0f / 512.0f) + L2GAMMA;
    float invf = exp2f(-(float)p * L2E4_512);
    float lf = (float)l;
    float s, c;
    sincosf(lf * invf, &s, &c);
    float g = exp2f((mode == 0 ? lf : -lf) * coeff);
    T[idx] = make_float2(c * g, s * g);
}

// ---------------------------------------------------------------------------
// Prep: fp32 -> bf16 cast of X
// ---------------------------------------------------------------------------
__global__ __launch_bounds__(256) void cast_x_kernel(
    const float4* __restrict__ X, short4v* __restrict__ Xb, int n4)
{
    int i = blockIdx.x * 256 + threadIdx.x;
    if (i < n4) {
        float4 v = X[i];
        short4v o;
        o.x = (short)f2b(v.x); o.y = (short)f2b(v.y);
        o.z = (short)f2b(v.z); o.w = (short)f2b(v.w);
        Xb[i] = o;
    }
}

// ---------------------------------------------------------------------------
// Prep: W (fp32 [K][N]) -> Wt (bf16 [N][K]) for all three weights
// ---------------------------------------------------------------------------
__global__ __launch_bounds__(256) void wtrans_kernel(
    const float* __restrict__ Wq, const float* __restrict__ Wk,
    const float* __restrict__ Wv, ushort_t* __restrict__ Wt)
{
    const float* W = blockIdx.z == 0 ? Wq : blockIdx.z == 1 ? Wk : Wv;
    ushort_t* O = Wt + (size_t)blockIdx.z * (DMODEL * DMODEL);
    __shared__ float t[32][33];
    const int x = threadIdx.x & 31, y = (threadIdx.x >> 5) * 4;
    const int k0 = blockIdx.y * 32, n0 = blockIdx.x * 32;
    #pragma unroll
    for (int j = 0; j < 4; ++j)
        t[y + j][x] = W[(size_t)(k0 + y + j) * DMODEL + n0 + x];
    __syncthreads();
    #pragma unroll
    for (int j = 0; j < 4; ++j)
        O[(size_t)(n0 + y + j) * DMODEL + k0 + x] = f2b(t[x][y + j]);
}

// ---------------------------------------------------------------------------
// Stage 1 (v7): QKV projection, 16x16x32 core (0.5 ds_reads/MFMA) + the
// double-buffered counted-vmcnt loop (no per-iter vmcnt(0) drain).
// 128x128 tile, 256 threads (4 waves, 2x2 of 64x64), 4x4 fragment grid.
// Operand layout (16x16x32): lane holds M/N index = lane&15, k-group =
// lane>>4 (8 elems each); C/D: col = lane&15 (+fc*16), row = (lane>>4)*4 + q
// (+fr*16)  [m89-verified].
// ---------------------------------------------------------------------------
__global__ __launch_bounds__(256) void qkv16_kernel(
    const ushort_t* __restrict__ Xb, const ushort_t* __restrict__ Wt,
    const float2* __restrict__ Tab,
    ushort_t* __restrict__ Q, ushort_t* __restrict__ Ko, ushort_t* __restrict__ Vt)
{
    __shared__ ushort_t smem[32768];        // 64 KB: A dbuf 32 KB | B dbuf 32 KB
    ushort_t* As = smem;                    // [2][128][64]
    ushort_t* Bs = smem + 16384;            // [2][128][64]

    // XCD-bijective swizzle (grid % 8 == 0) + 8x8 supertile decode
    const int nwg = gridDim.x;
    const int orig = blockIdx.x;
    const int lin = (orig & 7) * (nwg >> 3) + (orig >> 3);
    const int inner = lin & 63;
    const int sup = lin >> 6;
    const int c = (sup % 3) * 8 + (inner & 7);     // 0..23
    const int r = (sup / 3) * 8 + (inner >> 3);
    const int mode = c >> 3;
    const int c0 = (c & 7) * BN;
    const int row0 = r * BM;

    const int tid = threadIdx.x;
    const int wave = tid >> 6, lane = tid & 63;
    const int wm = wave >> 1, wn = wave & 1;
    const int l15 = lane & 15, l4g = lane >> 4, l7 = lane & 7;

    // staging: 16B chunks, XOR-swizzled by row&7, 32-bit voffsets
    const int srow = lane >> 3;
    const int scol = ((lane & 7) ^ srow) * 8;
    const char* gA = (const char*)Xb;
    const char* gB = (const char*)(Wt + (size_t)mode * (DMODEL * DMODEL));
    unsigned aoff[4], boff[4];
    #pragma unroll
    for (int L = 0; L < 4; ++L) {
        const int rr = (wave * 4 + L) * 8 + srow;       // 0..127
        aoff[L] = (unsigned)(((row0 + rr) * DMODEL + scol) * 2);
        boff[L] = (unsigned)(((c0 + rr) * DMODEL + scol) * 2);
    }
    const int ldst = srow * BK + (lane & 7) * 8;        // == lane*16 bytes

    // compute-read bases: frag f at k-half h:
    //   elem = (q64 + f*16 + l15)*64 + ((h*4 + l4g) ^ l7)*8
    int aBase[2], bBase[2];
    #pragma unroll
    for (int h = 0; h < 2; ++h) {
        const int ch = ((h * 4 + l4g) ^ l7) * 8;
        aBase[h] = (wm * 64 + l15) * BK + ch;
        bBase[h] = (wn * 64 + l15) * BK + ch;
    }

    float4v acc[4][4] = {};

    // stage K-tile 0 -> buf 0
    #pragma unroll
    for (int L = 0; L < 4; ++L) {
        GLOAD_LDS16(gA + aoff[L], As + (wave * 4 + L) * (8 * BK) + ldst);
        GLOAD_LDS16(gB + boff[L], Bs + (wave * 4 + L) * (8 * BK) + ldst);
        aoff[L] += 2 * BK; boff[L] += 2 * BK;
    }

    #pragma unroll 2
    for (int k = 0; k < 16; ++k) {
        const int cur = (k & 1) * (BM * BK);
        const int nxt = ((k + 1) & 1) * (BM * BK);
        if (k < 15) {
            #pragma unroll
            for (int L = 0; L < 4; ++L) {
                GLOAD_LDS16(gA + aoff[L], As + nxt + (wave * 4 + L) * (8 * BK) + ldst);
                GLOAD_LDS16(gB + boff[L], Bs + nxt + (wave * 4 + L) * (8 * BK) + ldst);
                aoff[L] += 2 * BK; boff[L] += 2 * BK;
            }
            asm volatile("s_waitcnt vmcnt(8)" ::: "memory");
        } else {
            asm volatile("s_waitcnt vmcnt(0)" ::: "memory");
        }
        __builtin_amdgcn_s_barrier();
        asm volatile("" ::: "memory");

        #pragma unroll
        for (int h = 0; h < 2; ++h) {
            short8 a[4], b[4];
            #pragma unroll
            for (int f = 0; f < 4; ++f) {
                a[f] = *(const short8*)(As + cur + aBase[h] + f * (16 * BK));
                b[f] = *(const short8*)(Bs + cur + bBase[h] + f * (16 * BK));
            }
            #pragma unroll
            for (int fr = 0; fr < 4; ++fr)
                #pragma unroll
                for (int fc = 0; fc < 4; ++fc)
                    acc[fr][fc] = MFMA16(a[fr], b[fc], acc[fr][fc], 0, 0, 0);
        }
        asm volatile("" ::: "memory");
        __builtin_amdgcn_s_barrier();
    }

    const int rB = row0 + wm * 64 + l4g * 4;   // + fr*16 + q
    const int cB = c0 + wn * 64 + l15;         // + fc*16

    if (mode < 2) {
        ushort_t* O = (mode == 0) ? Q : Ko;
        const float2* Tm = Tab + (size_t)mode * (512 * 2048);
        #pragma unroll
        for (int fc = 0; fc < 4; ++fc) {
            const int col = cB + fc * 16;
            const float2* tp = Tm + ((size_t)(col >> 1) << 11);
            #pragma unroll
            for (int fr = 0; fr < 4; ++fr) {
                const int row = rB + fr * 16;
                const int l0 = row & 2047;                   // multiple of 4
                float4 t01 = *(const float4*)(tp + l0);      // (c0,s0,c1,s1)
                float4 t23 = *(const float4*)(tp + l0 + 2);  // (c2,s2,c3,s3)
                float cs[8] = {t01.x, t01.y, t01.z, t01.w,
                               t23.x, t23.y, t23.z, t23.w};
                #pragma unroll
                for (int q = 0; q < 4; ++q) {
                    float v  = acc[fr][fc][q];
                    float pv = __shfl_xor(v, 1);   // lanes l,l^1 = cols c,c^1
                    float cc = cs[2 * q], ss = cs[2 * q + 1];
                    float res = (lane & 1) ? fmaf(v, cc, pv * ss)
                                           : fmaf(v, cc, -pv * ss);
                    O[(size_t)(row + q) * DMODEL + col] = f2b(res);
                }
            }
        }
    } else {
        // V: transpose tile in LDS (bf16, padded rows), then contiguous stores
        __syncthreads();   // staging fully drained (vmcnt(0) at last iter)
        #pragma unroll
        for (int fc = 0; fc < 4; ++fc)
            #pragma unroll
            for (int fr = 0; fr < 4; ++fr) {
                short4v pk;
                pk.x = (short)f2b(acc[fr][fc][0]);
                pk.y = (short)f2b(acc[fr][fc][1]);
                pk.z = (short)f2b(acc[fr][fc][2]);
                pk.w = (short)f2b(acc[fr][fc][3]);
                *(short4v*)(smem + (wn * 64 + fc * 16 + l15) * TPAD
                                 + wm * 64 + fr * 16 + l4g * 4) = pk;
            }
        __syncthreads();
        // thread t: col = t>>1, row-half = (t&1)*64; 128 B contiguous stores
        const int t = threadIdx.x;
        const int colV = c0 + (t >> 1);
        const int lhalf = (t & 1) * 64;
        const int b = row0 >> 11, lpos0 = (row0 & 2047) + lhalf;
        #pragma unroll
        for (int i = 0; i < 8; ++i) {
            short8 vv = *(const short8*)(smem + (t >> 1) * TPAD + lhalf + i * 8);
            *(short8*)(Vt + (size_t)b * (LSEQ * DMODEL)
                          + (size_t)colV * LSEQ + lpos0 + i * 8) = vv;
        }
    }
}

// ---------------------------------------------------------------------------
// Stage 2: S = Q-hat . K-hat^T (decay pre-folded), banded: only tiles with
// bi-2 <= bj <= bi. 45 tiles per batch.
// ---------------------------------------------------------------------------
__global__ __launch_bounds__(256, 2) void score_kernel(
    const ushort_t* __restrict__ Q, const ushort_t* __restrict__ Kc,
    ushort_t* __restrict__ S)
{
    const int t = blockIdx.x, z = blockIdx.z;
    int bi, bj;
    if (t < 3) { bi = (t > 0); bj = t - (t > 0); }
    else { int u = t - 3; bi = 2 + u / 3; bj = bi - 2 + u % 3; }

    __shared__ ushort_t As[2 * BM * BK], Bs[2 * BN * BK];   // 64 KB dbuf
    floatx16 acc[2][2] = {};
    const size_t zoff = (size_t)z * (LSEQ * DMODEL);
    gemm_core(Q + zoff, DMODEL, bi * BM, Kc + zoff, DMODEL, bj * BN,
              DMODEL, As, Bs, acc);

    const int wave = threadIdx.x >> 6, lane = threadIdx.x & 63;
    const int wm = wave >> 1, wn = wave & 1;
    const int l31 = lane & 31, half = lane >> 5;
    const int nBase = bi * BM + wm * 64 + 4 * half;
    const int mBase = bj * BN + wn * 64 + l31;
    ushort_t* Sz = S + (size_t)z * LSEQ * LSEQ;
    #pragma unroll
    for (int mi = 0; mi < 2; ++mi)
        #pragma unroll
        for (int ni = 0; ni < 2; ++ni) {
            int m = mBase + ni * 32;
            #pragma unroll
            for (int rg = 0; rg < 4; ++rg)
                #pragma unroll
                for (int q = 0; q < 4; ++q) {
                    int n = nBase + mi * 32 + 8 * rg + q;
                    Sz[(size_t)n * LSEQ + m] =
                        (m <= n) ? f2b(acc[mi][ni][rg * 4 + q]) : (ushort_t)0;
                }
        }
}

// ---------------------------------------------------------------------------
// Stage 3: O = S @ V, banded k-window [max(0,(bi-2)*128), (bi+1)*128).
// ---------------------------------------------------------------------------
__global__ __launch_bounds__(256, 2) void av_kernel(
    const ushort_t* __restrict__ S, const ushort_t* __restrict__ Vt,
    float* __restrict__ Out)
{
    const int bx = blockIdx.x, bi = blockIdx.y, z = blockIdx.z;
    const int kLo = (bi >= 2) ? (bi - 2) * BM : 0;
    const int kW  = (bi + 1) * BM - kLo;          // 128, 256, or 384
    __shared__ ushort_t As[2 * BM * BK], Bs[2 * BN * BK];   // 64 KB dbuf
    floatx16 acc[2][2] = {};
    gemm_core(S + (size_t)z * LSEQ * LSEQ + kLo, LSEQ, bi * BM,
              Vt + (size_t)z * (LSEQ * DMODEL) + kLo, LSEQ, bx * BN,
              kW, As, Bs, acc);

    const int wave = threadIdx.x >> 6, lane = threadIdx.x & 63;
    const int wm = wave >> 1, wn = wave & 1;
    const int l31 = lane & 31, half = lane >> 5;
    const int rBase = bi * BM + wm * 64 + 4 * half;
    const int cBase = bx * BN + wn * 64 + l31;
    float* Oz = Out + (size_t)z * (LSEQ * DMODEL);
    #pragma unroll
    for (int mi = 0; mi < 2; ++mi)
        #pragma unroll
        for (int ni = 0; ni < 2; ++ni)
            #pragma unroll
            for (int rg = 0; rg < 4; ++rg)
                #pragma unroll
                for (int q = 0; q < 4; ++q)
                    Oz[(size_t)(rBase + mi * 32 + 8 * rg + q) * DMODEL
                       + cBase + ni * 32] = acc[mi][ni][rg * 4 + q];
}

// ---------------------------------------------------------------------------
extern "C" void kernel_launch(void* const* d_in, const int* in_sizes, int n_in,
                              void* d_out, int out_size, void* d_ws, size_t ws_size,
                              hipStream_t stream)
{
    const float* X  = (const float*)d_in[0];
    const float* Wq = (const float*)d_in[1];
    const float* Wk = (const float*)d_in[2];
    const float* Wv = (const float*)d_in[3];
    float* out = (float*)d_out;

    const size_t LH  = (size_t)LSEQ * DMODEL;     // 2,097,152 elems / batch
    const size_t WSZ = (size_t)DMODEL * DMODEL;   // 1,048,576 elems / weight
    const size_t SSZ = (size_t)LSEQ * LSEQ;       // 4,194,304 elems / batch
    const size_t TABN = (size_t)2 * 512 * 2048;   // float2 entries

    size_t need4 = TABN * 8 + 2 * (3 * WSZ + 4 * (4 * LH + SSZ));  // ~124 MB
    const int bs = (ws_size >= need4) ? 4 : 1;

    float2* Tab = (float2*)d_ws;
    ushort_t* ws16 = (ushort_t*)(Tab + TABN);
    ushort_t* Wt = ws16;
    ushort_t* Xb = Wt + 3 * WSZ;
    ushort_t* Q  = Xb + (size_t)bs * LH;
    ushort_t* Kb = Q  + (size_t)bs * LH;
    ushort_t* Vt = Kb + (size_t)bs * LH;
    ushort_t* S  = Vt + (size_t)bs * LH;

    xpos_table_kernel<<<dim3(TABN / 256), 256, 0, stream>>>(Tab);
    wtrans_kernel<<<dim3(32, 32, 3), 256, 0, stream>>>(Wq, Wk, Wv, Wt);

    for (int p = 0; p < 4 / bs; ++p) {
        const float* Xp = X + (size_t)p * bs * LH;
        cast_x_kernel<<<dim3(bs * 2048), 256, 0, stream>>>(
            (const float4*)Xp, (short4v*)Xb, bs * (int)(LH / 4));
        qkv16_kernel<<<dim3(24 * bs * 16), 256, 0, stream>>>(
            Xb, Wt, Tab, Q, Kb, Vt);
        score_kernel<<<dim3(45, 1, bs), 256, 0, stream>>>(Q, Kb, S);
        av_kernel<<<dim3(8, 16, bs), 256, 0, stream>>>(S, Vt,
            out + (size_t)p * bs * LH);
    }
}

// Round 8
// 196.530 us; speedup vs baseline: 1.0846x; 1.0269x over previous
//
#include <hip/hip_runtime.h>
#include <cmath>

typedef __attribute__((ext_vector_type(8))) short short8;
typedef __attribute__((ext_vector_type(4))) short short4v;
typedef __attribute__((ext_vector_type(4))) float float4v;
typedef unsigned short ushort_t;

#define LSEQ   2048
#define DMODEL 1024
#define BM 128
#define BN 128
#define BK 64
#define TPAD 136   // transpose LDS row stride (elems); 272 B, 16-B aligned

// log2(0.96875)
#define L2GAMMA (-0.045803595f)
// log2(10000)/512
#define L2E4_512 (0.0259525632f)

// float -> bf16 with round-to-nearest-even
__device__ __forceinline__ ushort_t f2b(float x) {
    union { float f; unsigned u; } v; v.f = x;
    unsigned r = v.u + 0x7fffu + ((v.u >> 16) & 1u);
    return (ushort_t)(r >> 16);
}

#define GLOAD_LDS16(gptr, lptr)                                                     \
    __builtin_amdgcn_global_load_lds(                                               \
        (const __attribute__((address_space(1))) unsigned int*)(gptr),              \
        (__attribute__((address_space(3))) unsigned int*)(lptr), 16, 0, 0)

#define MFMA16 __builtin_amdgcn_mfma_f32_16x16x32_bf16

// ---------------------------------------------------------------------------
// Shared GEMM core: 16x16x32 MFMA, 128x128 tile, 256 threads (4 waves, 2x2
// of 64x64), 4x4 fragment grid (0.5 ds_read_b128 per MFMA). DOUBLE-BUFFERED
// staging, counted vmcnt(8), raw barriers (no per-iter vmcnt(0) drain).
// As/Bs each 2*BM*BK ushorts. Ledger per thread per iter: enter with tile
// j's 8 loads in flight; issue j+1's 8 -> 16; vmcnt(8) retires j's; barrier;
// compute j; barrier. Overwrite of buf j+1 is safe: its last reads (iter
// j-1) completed before that iter's trailing barrier.
// Operand layout (16x16x32): lane M/N index = lane&15, k-group = lane>>4;
// C/D: col = lane&15 (+fc*16), row = (lane>>4)*4 + q (+fr*16) [m89].
// ---------------------------------------------------------------------------
__device__ __forceinline__ void gemm16_core(
    const ushort_t* __restrict__ Ag, int lda, int aRow0,
    const ushort_t* __restrict__ Bg, int ldb, int bRow0,
    int kDepth, ushort_t* As, ushort_t* Bs, float4v acc[4][4])
{
    const int tid  = threadIdx.x;
    const int wave = tid >> 6, lane = tid & 63;
    const int wm = wave >> 1, wn = wave & 1;
    const int l15 = lane & 15, l4g = lane >> 4, l7 = lane & 7;
    const int srow = lane >> 3;
    const int scol = ((lane & 7) ^ srow) * 8;     // XOR-swizzled source chunk

    const ushort_t* ap[4];
    const ushort_t* bp[4];
    #pragma unroll
    for (int L = 0; L < 4; ++L) {
        int r = (wave * 4 + L) * 8 + srow;        // 0..127
        ap[L] = Ag + (size_t)(aRow0 + r) * lda + scol;
        bp[L] = Bg + (size_t)(bRow0 + r) * ldb + scol;
    }
    const int ldst = srow * BK + (lane & 7) * 8;  // == lane*16 bytes

    int aBase[2], bBase[2];
    #pragma unroll
    for (int h = 0; h < 2; ++h) {
        const int ch = ((h * 4 + l4g) ^ l7) * 8;
        aBase[h] = (wm * 64 + l15) * BK + ch;
        bBase[h] = (wn * 64 + l15) * BK + ch;
    }

    const int nt = kDepth / BK;
    #pragma unroll
    for (int L = 0; L < 4; ++L) {                 // stage tile 0 -> buf 0
        GLOAD_LDS16(ap[L], As + (wave * 4 + L) * (8 * BK) + ldst);
        GLOAD_LDS16(bp[L], Bs + (wave * 4 + L) * (8 * BK) + ldst);
        ap[L] += BK; bp[L] += BK;
    }

    for (int j = 0; j < nt; ++j) {
        const int cur = (j & 1) * (BM * BK);
        const int nxt = ((j + 1) & 1) * (BM * BK);
        if (j + 1 < nt) {
            #pragma unroll
            for (int L = 0; L < 4; ++L) {
                GLOAD_LDS16(ap[L], As + nxt + (wave * 4 + L) * (8 * BK) + ldst);
                GLOAD_LDS16(bp[L], Bs + nxt + (wave * 4 + L) * (8 * BK) + ldst);
                ap[L] += BK; bp[L] += BK;
            }
            asm volatile("s_waitcnt vmcnt(8)" ::: "memory");
        } else {
            asm volatile("s_waitcnt vmcnt(0)" ::: "memory");
        }
        __builtin_amdgcn_s_barrier();
        asm volatile("" ::: "memory");

        #pragma unroll
        for (int h = 0; h < 2; ++h) {
            short8 a[4], b[4];
            #pragma unroll
            for (int f = 0; f < 4; ++f) {
                a[f] = *(const short8*)(As + cur + aBase[h] + f * (16 * BK));
                b[f] = *(const short8*)(Bs + cur + bBase[h] + f * (16 * BK));
            }
            #pragma unroll
            for (int fr = 0; fr < 4; ++fr)
                #pragma unroll
                for (int fc = 0; fc < 4; ++fc)
                    acc[fr][fc] = MFMA16(a[fr], b[fc], acc[fr][fc], 0, 0, 0);
        }
        asm volatile("" ::: "memory");
        __builtin_amdgcn_s_barrier();
    }
}

// ---------------------------------------------------------------------------
// Merged prep (single dispatch): blocks [0,8192) xpos tables; [8192,11264)
// weight transpose; [11264,19456) X fp32->bf16 cast. All outputs disjoint.
// ---------------------------------------------------------------------------
__global__ __launch_bounds__(256) void prep_kernel(
    float2* __restrict__ T,
    const float* __restrict__ Wq, const float* __restrict__ Wk,
    const float* __restrict__ Wv, ushort_t* __restrict__ Wt,
    const float4* __restrict__ X, short4v* __restrict__ Xb, int n4)
{
    __shared__ float t[32][33];
    const int bid = blockIdx.x;
    if (bid < 8192) {
        int idx = bid * 256 + threadIdx.x;   // 2*512*2048 entries
        int l = idx & 2047;
        int p = (idx >> 11) & 511;
        int mode = idx >> 20;
        float sv = (2.0f * (float)p + 409.6f) * (1.0f / 1433.6f);
        float coeff = log2f(sv) * (1.0f / 512.0f) + L2GAMMA;
        float invf = exp2f(-(float)p * L2E4_512);
        float lf = (float)l;
        float s, c;
        sincosf(lf * invf, &s, &c);
        float g = exp2f((mode == 0 ? lf : -lf) * coeff);
        T[idx] = make_float2(c * g, s * g);
    } else if (bid < 11264) {
        const int wb = bid - 8192;
        const int bz = wb >> 10;             // 0..2
        const int rem = wb & 1023;
        const int by = rem >> 5, bx = rem & 31;
        const float* W = bz == 0 ? Wq : bz == 1 ? Wk : Wv;
        ushort_t* O = Wt + (size_t)bz * (DMODEL * DMODEL);
        const int x = threadIdx.x & 31, y = (threadIdx.x >> 5) * 4;
        const int k0 = by * 32, n0 = bx * 32;
        #pragma unroll
        for (int j = 0; j < 4; ++j)
            t[y + j][x] = W[(size_t)(k0 + y + j) * DMODEL + n0 + x];
        __syncthreads();
        #pragma unroll
        for (int j = 0; j < 4; ++j)
            O[(size_t)(n0 + y + j) * DMODEL + k0 + x] = f2b(t[x][y + j]);
    } else {
        int i = (bid - 11264) * 256 + threadIdx.x;
        if (i < n4) {
            float4 v = X[i];
            short4v o;
            o.x = (short)f2b(v.x); o.y = (short)f2b(v.y);
            o.z = (short)f2b(v.z); o.w = (short)f2b(v.w);
            Xb[i] = o;
        }
    }
}

// ---------------------------------------------------------------------------
// Stage 1: QKV projection (unchanged from R7: 72.9 us, 707 TF).
// ---------------------------------------------------------------------------
__global__ __launch_bounds__(256) void qkv16_kernel(
    const ushort_t* __restrict__ Xb, const ushort_t* __restrict__ Wt,
    const float2* __restrict__ Tab,
    ushort_t* __restrict__ Q, ushort_t* __restrict__ Ko, ushort_t* __restrict__ Vt)
{
    __shared__ ushort_t smem[32768];        // 64 KB: A dbuf 32 KB | B dbuf 32 KB
    ushort_t* As = smem;                    // [2][128][64]
    ushort_t* Bs = smem + 16384;            // [2][128][64]

    // XCD-bijective swizzle (grid % 8 == 0) + 8x8 supertile decode
    const int nwg = gridDim.x;
    const int orig = blockIdx.x;
    const int lin = (orig & 7) * (nwg >> 3) + (orig >> 3);
    const int inner = lin & 63;
    const int sup = lin >> 6;
    const int c = (sup % 3) * 8 + (inner & 7);     // 0..23
    const int r = (sup / 3) * 8 + (inner >> 3);
    const int mode = c >> 3;
    const int c0 = (c & 7) * BN;
    const int row0 = r * BM;

    const int tid = threadIdx.x;
    const int wave = tid >> 6, lane = tid & 63;
    const int wm = wave >> 1, wn = wave & 1;
    const int l15 = lane & 15, l4g = lane >> 4, l7 = lane & 7;

    const int srow = lane >> 3;
    const int scol = ((lane & 7) ^ srow) * 8;
    const char* gA = (const char*)Xb;
    const char* gB = (const char*)(Wt + (size_t)mode * (DMODEL * DMODEL));
    unsigned aoff[4], boff[4];
    #pragma unroll
    for (int L = 0; L < 4; ++L) {
        const int rr = (wave * 4 + L) * 8 + srow;       // 0..127
        aoff[L] = (unsigned)(((row0 + rr) * DMODEL + scol) * 2);
        boff[L] = (unsigned)(((c0 + rr) * DMODEL + scol) * 2);
    }
    const int ldst = srow * BK + (lane & 7) * 8;        // == lane*16 bytes

    int aBase[2], bBase[2];
    #pragma unroll
    for (int h = 0; h < 2; ++h) {
        const int ch = ((h * 4 + l4g) ^ l7) * 8;
        aBase[h] = (wm * 64 + l15) * BK + ch;
        bBase[h] = (wn * 64 + l15) * BK + ch;
    }

    float4v acc[4][4] = {};

    #pragma unroll
    for (int L = 0; L < 4; ++L) {           // stage K-tile 0 -> buf 0
        GLOAD_LDS16(gA + aoff[L], As + (wave * 4 + L) * (8 * BK) + ldst);
        GLOAD_LDS16(gB + boff[L], Bs + (wave * 4 + L) * (8 * BK) + ldst);
        aoff[L] += 2 * BK; boff[L] += 2 * BK;
    }

    #pragma unroll 2
    for (int k = 0; k < 16; ++k) {
        const int cur = (k & 1) * (BM * BK);
        const int nxt = ((k + 1) & 1) * (BM * BK);
        if (k < 15) {
            #pragma unroll
            for (int L = 0; L < 4; ++L) {
                GLOAD_LDS16(gA + aoff[L], As + nxt + (wave * 4 + L) * (8 * BK) + ldst);
                GLOAD_LDS16(gB + boff[L], Bs + nxt + (wave * 4 + L) * (8 * BK) + ldst);
                aoff[L] += 2 * BK; boff[L] += 2 * BK;
            }
            asm volatile("s_waitcnt vmcnt(8)" ::: "memory");
        } else {
            asm volatile("s_waitcnt vmcnt(0)" ::: "memory");
        }
        __builtin_amdgcn_s_barrier();
        asm volatile("" ::: "memory");

        #pragma unroll
        for (int h = 0; h < 2; ++h) {
            short8 a[4], b[4];
            #pragma unroll
            for (int f = 0; f < 4; ++f) {
                a[f] = *(const short8*)(As + cur + aBase[h] + f * (16 * BK));
                b[f] = *(const short8*)(Bs + cur + bBase[h] + f * (16 * BK));
            }
            #pragma unroll
            for (int fr = 0; fr < 4; ++fr)
                #pragma unroll
                for (int fc = 0; fc < 4; ++fc)
                    acc[fr][fc] = MFMA16(a[fr], b[fc], acc[fr][fc], 0, 0, 0);
        }
        asm volatile("" ::: "memory");
        __builtin_amdgcn_s_barrier();
    }

    const int rB = row0 + wm * 64 + l4g * 4;   // + fr*16 + q
    const int cB = c0 + wn * 64 + l15;         // + fc*16

    if (mode < 2) {
        ushort_t* O = (mode == 0) ? Q : Ko;
        const float2* Tm = Tab + (size_t)mode * (512 * 2048);
        #pragma unroll
        for (int fc = 0; fc < 4; ++fc) {
            const int col = cB + fc * 16;
            const float2* tp = Tm + ((size_t)(col >> 1) << 11);
            #pragma unroll
            for (int fr = 0; fr < 4; ++fr) {
                const int row = rB + fr * 16;
                const int l0 = row & 2047;                   // multiple of 4
                float4 t01 = *(const float4*)(tp + l0);      // (c0,s0,c1,s1)
                float4 t23 = *(const float4*)(tp + l0 + 2);  // (c2,s2,c3,s3)
                float cs[8] = {t01.x, t01.y, t01.z, t01.w,
                               t23.x, t23.y, t23.z, t23.w};
                #pragma unroll
                for (int q = 0; q < 4; ++q) {
                    float v  = acc[fc][0][0];  // placeholder avoided below
                    v = acc[fr][fc][q];
                    float pv = __shfl_xor(v, 1);   // lanes l,l^1 = cols c,c^1
                    float cc = cs[2 * q], ss = cs[2 * q + 1];
                    float res = (lane & 1) ? fmaf(v, cc, pv * ss)
                                           : fmaf(v, cc, -pv * ss);
                    O[(size_t)(row + q) * DMODEL + col] = f2b(res);
                }
            }
        }
    } else {
        // V: transpose tile in LDS (bf16, padded rows), then contiguous stores
        __syncthreads();   // staging fully drained (vmcnt(0) at last iter)
        #pragma unroll
        for (int fc = 0; fc < 4; ++fc)
            #pragma unroll
            for (int fr = 0; fr < 4; ++fr) {
                short4v pk;
                pk.x = (short)f2b(acc[fr][fc][0]);
                pk.y = (short)f2b(acc[fr][fc][1]);
                pk.z = (short)f2b(acc[fr][fc][2]);
                pk.w = (short)f2b(acc[fr][fc][3]);
                *(short4v*)(smem + (wn * 64 + fc * 16 + l15) * TPAD
                                 + wm * 64 + fr * 16 + l4g * 4) = pk;
            }
        __syncthreads();
        const int t = threadIdx.x;
        const int colV = c0 + (t >> 1);
        const int lhalf = (t & 1) * 64;
        const int b = row0 >> 11, lpos0 = (row0 & 2047) + lhalf;
        #pragma unroll
        for (int i = 0; i < 8; ++i) {
            short8 vv = *(const short8*)(smem + (t >> 1) * TPAD + lhalf + i * 8);
            *(short8*)(Vt + (size_t)b * (LSEQ * DMODEL)
                          + (size_t)colV * LSEQ + lpos0 + i * 8) = vv;
        }
    }
}

// ---------------------------------------------------------------------------
// Stage 2: S = Q-hat . K-hat^T (decay pre-folded), banded (45 tiles/batch),
// now on the 16x16 dbuf core.
// ---------------------------------------------------------------------------
__global__ __launch_bounds__(256) void score_kernel(
    const ushort_t* __restrict__ Q, const ushort_t* __restrict__ Kc,
    ushort_t* __restrict__ S)
{
    const int t = blockIdx.x, z = blockIdx.z;
    int bi, bj;
    if (t < 3) { bi = (t > 0); bj = t - (t > 0); }
    else { int u = t - 3; bi = 2 + u / 3; bj = bi - 2 + u % 3; }

    __shared__ ushort_t As[2 * BM * BK], Bs[2 * BN * BK];   // 64 KB dbuf
    float4v acc[4][4] = {};
    const size_t zoff = (size_t)z * (LSEQ * DMODEL);
    gemm16_core(Q + zoff, DMODEL, bi * BM, Kc + zoff, DMODEL, bj * BN,
                DMODEL, As, Bs, acc);

    const int wave = threadIdx.x >> 6, lane = threadIdx.x & 63;
    const int wm = wave >> 1, wn = wave & 1;
    const int l15 = lane & 15, l4g = lane >> 4;
    const int nB = bi * BM + wm * 64 + l4g * 4;   // query row
    const int mB = bj * BN + wn * 64 + l15;       // key col
    ushort_t* Sz = S + (size_t)z * LSEQ * LSEQ;
    #pragma unroll
    for (int fr = 0; fr < 4; ++fr)
        #pragma unroll
        for (int fc = 0; fc < 4; ++fc) {
            const int m = mB + fc * 16;
            #pragma unroll
            for (int q = 0; q < 4; ++q) {
                const int n = nB + fr * 16 + q;
                Sz[(size_t)n * LSEQ + m] =
                    (m <= n) ? f2b(acc[fr][fc][q]) : (ushort_t)0;
            }
        }
}

// ---------------------------------------------------------------------------
// Stage 3: O = S @ V, banded k-window [max(0,(bi-2)*128), (bi+1)*128),
// 16x16 dbuf core.
// ---------------------------------------------------------------------------
__global__ __launch_bounds__(256) void av_kernel(
    const ushort_t* __restrict__ S, const ushort_t* __restrict__ Vt,
    float* __restrict__ Out)
{
    const int bx = blockIdx.x, bi = blockIdx.y, z = blockIdx.z;
    const int kLo = (bi >= 2) ? (bi - 2) * BM : 0;
    const int kW  = (bi + 1) * BM - kLo;          // 128, 256, or 384
    __shared__ ushort_t As[2 * BM * BK], Bs[2 * BN * BK];   // 64 KB dbuf
    float4v acc[4][4] = {};
    gemm16_core(S + (size_t)z * LSEQ * LSEQ + kLo, LSEQ, bi * BM,
                Vt + (size_t)z * (LSEQ * DMODEL) + kLo, LSEQ, bx * BN,
                kW, As, Bs, acc);

    const int wave = threadIdx.x >> 6, lane = threadIdx.x & 63;
    const int wm = wave >> 1, wn = wave & 1;
    const int l15 = lane & 15, l4g = lane >> 4;
    const int rB = bi * BM + wm * 64 + l4g * 4;
    const int cB = bx * BN + wn * 64 + l15;
    float* Oz = Out + (size_t)z * (LSEQ * DMODEL);
    #pragma unroll
    for (int fr = 0; fr < 4; ++fr)
        #pragma unroll
        for (int fc = 0; fc < 4; ++fc)
            #pragma unroll
            for (int q = 0; q < 4; ++q)
                Oz[(size_t)(rB + fr * 16 + q) * DMODEL + cB + fc * 16] =
                    acc[fr][fc][q];
}

// ---------------------------------------------------------------------------
extern "C" void kernel_launch(void* const* d_in, const int* in_sizes, int n_in,
                              void* d_out, int out_size, void* d_ws, size_t ws_size,
                              hipStream_t stream)
{
    const float* X  = (const float*)d_in[0];
    const float* Wq = (const float*)d_in[1];
    const float* Wk = (const float*)d_in[2];
    const float* Wv = (const float*)d_in[3];
    float* out = (float*)d_out;

    const size_t LH  = (size_t)LSEQ * DMODEL;     // 2,097,152 elems / batch
    const size_t WSZ = (size_t)DMODEL * DMODEL;   // 1,048,576 elems / weight
    const size_t SSZ = (size_t)LSEQ * LSEQ;       // 4,194,304 elems / batch
    const size_t TABN = (size_t)2 * 512 * 2048;   // float2 entries

    size_t need4 = TABN * 8 + 2 * (3 * WSZ + 4 * (4 * LH + SSZ));  // ~124 MB
    const int bs = (ws_size >= need4) ? 4 : 1;

    float2* Tab = (float2*)d_ws;
    ushort_t* ws16 = (ushort_t*)(Tab + TABN);
    ushort_t* Wt = ws16;
    ushort_t* Xb = Wt + 3 * WSZ;
    ushort_t* Q  = Xb + (size_t)bs * LH;
    ushort_t* Kb = Q  + (size_t)bs * LH;
    ushort_t* Vt = Kb + (size_t)bs * LH;
    ushort_t* S  = Vt + (size_t)bs * LH;

    if (bs == 4) {
        // single merged prep dispatch: tables + W transpose + X cast (4 batches)
        prep_kernel<<<dim3(19456), 256, 0, stream>>>(
            Tab, Wq, Wk, Wv, Wt, (const float4*)X, (short4v*)Xb,
            (int)(4 * LH / 4));
        qkv16_kernel<<<dim3(24 * 4 * 16), 256, 0, stream>>>(
            Xb, Wt, Tab, Q, Kb, Vt);
        score_kernel<<<dim3(45, 1, 4), 256, 0, stream>>>(Q, Kb, S);
        av_kernel<<<dim3(8, 16, 4), 256, 0, stream>>>(S, Vt, out);
    } else {
        // fallback: small workspace, 4 sequential passes
        prep_kernel<<<dim3(11264), 256, 0, stream>>>(
            Tab, Wq, Wk, Wv, Wt, (const float4*)X, (short4v*)Xb, 0);
        for (int p = 0; p < 4; ++p) {
            const float* Xp = X + (size_t)p * LH;
            prep_kernel<<<dim3(2048), 256, 0, stream>>>(
                Tab, Wq, Wk, Wv, Wt,   // blocks < 8192: rewrites table (benign)
                (const float4*)Xp, (short4v*)Xb, (int)(LH / 4));
            qkv16_kernel<<<dim3(24 * 16), 256, 0, stream>>>(
                Xb, Wt, Tab, Q, Kb, Vt);
            score_kernel<<<dim3(45, 1, 1), 256, 0, stream>>>(Q, Kb, S);
            av_kernel<<<dim3(8, 16, 1), 256, 0, stream>>>(S, Vt,
                out + (size_t)p * LH);
        }
    }
}